// Round 4
// baseline (48.537 us; speedup 1.0000x reference)
//
#include <hip/hip_runtime.h>

#define N_TOK 262144
#define DDIM  256
#define CCLS  50001

// K1: build per-class linked lists over all rows.
// heads[] pre-set to -1 via memset(0xFF).
__global__ void build_kernel(const int* __restrict__ trow,
                             int* __restrict__ heads,
                             int* __restrict__ next) {
    int i = blockIdx.x * blockDim.x + threadIdx.x;
    if (i < N_TOK) {
        const int t = trow[i];
        const int old = atomicExch(&heads[t], i);
        next[i] = old;                    // coalesced 1 MB write
    }
}

// K2 (after out <- center d2d copy): one wave per target entry.
// Walk the class's list, sum rows (lane = one float4 of the row), write mean.
// Duplicate target entries compute identical means -> identical stores (benign).
__global__ void update_kernel(const float* __restrict__ in,
                              const int* __restrict__ tgt, int n_tgt,
                              const int* __restrict__ heads,
                              const int* __restrict__ next,
                              float* __restrict__ out) {
    const int wid  = threadIdx.x >> 6;          // 4 waves/block
    const int lane = threadIdx.x & 63;
    const int i = blockIdx.x * 4 + wid;
    if (i >= n_tgt) return;

    const int c = tgt[i];
    const int head = heads[c];
    if (head == -1) return;                     // counts==0: keep center copy

    float4 acc = {0.f, 0.f, 0.f, 0.f};
    int cnt = 0;
    for (int row = head; row != -1; row = next[row]) {
        const float4 v =
            reinterpret_cast<const float4*>(in)[(long long)row * (DDIM / 4) + lane];
        acc.x += v.x; acc.y += v.y; acc.z += v.z; acc.w += v.w;
        ++cnt;
    }
    const float inv = 1.0f / (float)cnt;
    float4 r;
    r.x = acc.x * inv; r.y = acc.y * inv; r.z = acc.z * inv; r.w = acc.w * inv;
    reinterpret_cast<float4*>(out)[(long long)c * (DDIM / 4) + lane] = r;
}

extern "C" void kernel_launch(void* const* d_in, const int* in_sizes, int n_in,
                              void* d_out, int out_size, void* d_ws, size_t ws_size,
                              hipStream_t stream) {
    const float* inputs_row = (const float*)d_in[0];
    const float* center     = (const float*)d_in[1];
    const int*   target_row = (const int*)d_in[2];
    const int*   target     = (const int*)d_in[3];
    const int    n_target   = in_sizes[3];

    float* out = (float*)d_out;

    // ws layout (ints): heads[CCLS] | next[N_TOK]
    int* heads = (int*)d_ws;
    int* next  = heads + CCLS;

    // heads = -1 (0xFF bytes).
    hipMemsetAsync(heads, 0xFF, (size_t)CCLS * sizeof(int), stream);

    // Build linked lists.
    build_kernel<<<(N_TOK + 255) / 256, 256, 0, stream>>>(target_row, heads, next);

    // Bulk copy center -> out at copy-kernel bandwidth (~7 TB/s).
    hipMemcpyAsync(out, center, (size_t)CCLS * DDIM * sizeof(float),
                   hipMemcpyDeviceToDevice, stream);

    // Overwrite updated classes only.
    update_kernel<<<(n_target + 3) / 4, 256, 0, stream>>>(inputs_row, target, n_target,
                                                          heads, next, out);
}

// Round 5
// 46.515 us; speedup vs baseline: 1.0435x; 1.0435x over previous
//
#include <hip/hip_runtime.h>

#define N_TOK 262144
#define DDIM  256
#define CCLS  50001
#define BUILD_BLOCKS 1024                    // 1024*256 = 262144 threads
#define COPY_BLOCKS  2048
#define TOTAL4 ((long long)CCLS * (DDIM / 4))  // 3,200,064 float4

// Fat kernel: first BUILD_BLOCKS blocks build per-class linked lists
// (heads pre-set to -1); remaining blocks grid-stride copy center -> out.
// The two halves are independent; co-residency hides the build's atomic
// latency under the copy's bandwidth stream.
__global__ void build_and_copy_kernel(const int* __restrict__ trow,
                                      int* __restrict__ heads,
                                      int* __restrict__ next,
                                      const float* __restrict__ center,
                                      float* __restrict__ out) {
    if (blockIdx.x < BUILD_BLOCKS) {
        const int i = blockIdx.x * blockDim.x + threadIdx.x;   // < N_TOK exactly
        const int t = trow[i];
        const int old = atomicExch(&heads[t], i);
        next[i] = old;                        // coalesced 1 MB write
    } else {
        const long long tid =
            (long long)(blockIdx.x - BUILD_BLOCKS) * blockDim.x + threadIdx.x;
        const long long stride = (long long)COPY_BLOCKS * blockDim.x;
        for (long long j = tid; j < TOTAL4; j += stride) {
            reinterpret_cast<float4*>(out)[j] =
                reinterpret_cast<const float4*>(center)[j];
        }
    }
}

// One wave per target entry: walk the class's list, sum rows (lane = one
// float4 of the row), overwrite out[c] with the mean. Duplicate target
// entries store identical values (benign). head == -1 => keep center copy.
__global__ void update_kernel(const float* __restrict__ in,
                              const int* __restrict__ tgt, int n_tgt,
                              const int* __restrict__ heads,
                              const int* __restrict__ next,
                              float* __restrict__ out) {
    const int wid  = threadIdx.x >> 6;        // 4 waves/block
    const int lane = threadIdx.x & 63;
    const int i = blockIdx.x * 4 + wid;
    if (i >= n_tgt) return;

    const int c = tgt[i];
    const int head = heads[c];
    if (head == -1) return;                   // counts==0: keep center copy

    float4 acc = {0.f, 0.f, 0.f, 0.f};
    int cnt = 0;
    for (int row = head; row != -1; row = next[row]) {
        const float4 v =
            reinterpret_cast<const float4*>(in)[(long long)row * (DDIM / 4) + lane];
        acc.x += v.x; acc.y += v.y; acc.z += v.z; acc.w += v.w;
        ++cnt;
    }
    const float inv = 1.0f / (float)cnt;
    float4 r;
    r.x = acc.x * inv; r.y = acc.y * inv; r.z = acc.z * inv; r.w = acc.w * inv;
    reinterpret_cast<float4*>(out)[(long long)c * (DDIM / 4) + lane] = r;
}

extern "C" void kernel_launch(void* const* d_in, const int* in_sizes, int n_in,
                              void* d_out, int out_size, void* d_ws, size_t ws_size,
                              hipStream_t stream) {
    const float* inputs_row = (const float*)d_in[0];
    const float* center     = (const float*)d_in[1];
    const int*   target_row = (const int*)d_in[2];
    const int*   target     = (const int*)d_in[3];
    const int    n_target   = in_sizes[3];

    float* out = (float*)d_out;

    // ws layout (ints): heads[CCLS] | next[N_TOK]
    int* heads = (int*)d_ws;
    int* next  = heads + CCLS;

    // heads = -1 (0xFF bytes).
    hipMemsetAsync(heads, 0xFF, (size_t)CCLS * sizeof(int), stream);

    // Build linked lists + bulk copy center -> out, one dispatch.
    build_and_copy_kernel<<<BUILD_BLOCKS + COPY_BLOCKS, 256, 0, stream>>>(
        target_row, heads, next, center, out);

    // Overwrite updated classes only.
    update_kernel<<<(n_target + 3) / 4, 256, 0, stream>>>(inputs_row, target, n_target,
                                                          heads, next, out);
}